// Round 3
// baseline (2055.425 us; speedup 1.0000x reference)
//
#include <hip/hip_runtime.h>
#include <hip/hip_bf16.h>
#include <stdint.h>

// HybridCodebook: xn = normalize(x); cb = [normalize(sem); normalize(learn)]
// logits = xn @ cb^T ; indices = argmax ; z_q = cb[indices]; losses.
// Outputs (FLOAT32, concatenated flat in return order):
//   logits [8192*8320], indices [8192], z_q [8192*1024], z_q_st [8192*1024],
//   vq_loss, commitment_loss, quant_loss.
// Evidence for f32 out: identical 8320.048 error in rounds 1-2 = bf16 index
// writes landing at float element 34,078,720 inside the f32 logits chunk.

#define N_TOK   8192
#define DIM     1024
#define N_SEM   8192
#define N_LEARN 128
#define N_CODE  (N_SEM + N_LEARN)   // 8320

// ---- K0: zero argmax keys + loss accumulators (ws is poisoned 0xAA) ----
__global__ void k_init(unsigned long long* keys, float* accum) {
    int i = blockIdx.x * blockDim.x + threadIdx.x;
    if (i < N_TOK) keys[i] = 0ULL;
    if (i < 4) accum[i] = 0.f;
}

// ---- K1: per-row inverse L2 norm (1 / max(||row||, 1e-8)) ----
__global__ __launch_bounds__(256) void k_norms(const float* __restrict__ in,
                                               float* __restrict__ invn) {
    const int row = blockIdx.x;
    const int t = threadIdx.x;
    float4 v = ((const float4*)(in + (size_t)row * DIM))[t];
    float ss = v.x*v.x + v.y*v.y + v.z*v.z + v.w*v.w;
    #pragma unroll
    for (int off = 32; off > 0; off >>= 1) ss += __shfl_xor(ss, off);
    __shared__ float red[4];
    if ((t & 63) == 0) red[t >> 6] = ss;
    __syncthreads();
    if (t == 0) {
        float tot = red[0] + red[1] + red[2] + red[3];
        invn[row] = 1.f / fmaxf(sqrtf(tot), 1e-8f);
    }
}

// ---- K2: fp32 GEMM on RAW inputs, scale by invnorms in epilogue,
//          fused f32 logits store + per-row packed argmax atomicMax ----
#define TM 128
#define TN 128
#define TK 32

__global__ __launch_bounds__(256) void k_gemm_argmax(
    const float* __restrict__ X,          // raw x [N_TOK][DIM]
    const float* __restrict__ SEM,        // raw sem [N_SEM][DIM]
    const float* __restrict__ LRN,        // raw learnable [N_LEARN][DIM]
    const float* __restrict__ invnx,      // [N_TOK]
    const float* __restrict__ invnb,      // [N_CODE]
    float* __restrict__ logits,           // [N_TOK][N_CODE] f32
    unsigned long long* __restrict__ keys)
{
    __shared__ __align__(16) float As[TK][TM + 4];
    __shared__ __align__(16) float Bs[TK][TN + 4];
    const int t  = threadIdx.x;
    const int tx = t & 15;   // col group (8 cols)
    const int ty = t >> 4;   // row group (8 rows)
    const int row0 = blockIdx.x * TM;
    const int col0 = blockIdx.y * TN;

    float c[8][8];
    #pragma unroll
    for (int i = 0; i < 8; ++i)
        #pragma unroll
        for (int j = 0; j < 8; ++j) c[i][j] = 0.f;

    for (int k0 = 0; k0 < DIM; k0 += TK) {
        #pragma unroll
        for (int ld = 0; ld < 4; ++ld) {
            int ch = ld * 256 + t;   // 0..1023
            int r  = ch >> 3;        // 0..127
            int ks = ch & 7;         // float4 index inside 32-k window
            float4 va = *(const float4*)(X + (size_t)(row0 + r) * DIM + k0 + ks * 4);
            As[ks*4+0][r] = va.x; As[ks*4+1][r] = va.y;
            As[ks*4+2][r] = va.z; As[ks*4+3][r] = va.w;
            int bc = col0 + r;
            const float* brow = (bc < N_SEM)
                              ? (SEM + (size_t)bc * DIM)
                              : (LRN + (size_t)(bc - N_SEM) * DIM);
            float4 vb = *(const float4*)(brow + k0 + ks * 4);
            Bs[ks*4+0][r] = vb.x; Bs[ks*4+1][r] = vb.y;
            Bs[ks*4+2][r] = vb.z; Bs[ks*4+3][r] = vb.w;
        }
        __syncthreads();
        #pragma unroll
        for (int kk = 0; kk < TK; ++kk) {
            float4 a0 = *(const float4*)(&As[kk][ty*8]);
            float4 a1 = *(const float4*)(&As[kk][ty*8+4]);
            float4 b0 = *(const float4*)(&Bs[kk][tx*8]);
            float4 b1 = *(const float4*)(&Bs[kk][tx*8+4]);
            float a[8] = {a0.x,a0.y,a0.z,a0.w,a1.x,a1.y,a1.z,a1.w};
            float b[8] = {b0.x,b0.y,b0.z,b0.w,b1.x,b1.y,b1.z,b1.w};
            #pragma unroll
            for (int i = 0; i < 8; ++i)
                #pragma unroll
                for (int j = 0; j < 8; ++j)
                    c[i][j] = fmaf(a[i], b[j], c[i][j]);
        }
        __syncthreads();
    }

    // normalize: c[i][j] *= invnx[row] * invnb[col]
    float ia[8], ib[8];
    #pragma unroll
    for (int i = 0; i < 8; ++i) ia[i] = invnx[row0 + ty*8 + i];
    #pragma unroll
    for (int j = 0; j < 8; ++j) ib[j] = invnb[col0 + tx*8 + j];

    #pragma unroll
    for (int i = 0; i < 8; ++i) {
        const int row = row0 + ty*8 + i;
        float v = -3.4e38f; int col = 0;
        float cv[8];
        #pragma unroll
        for (int j = 0; j < 8; ++j) {
            cv[j] = c[i][j] * (ia[i] * ib[j]);
            if (cv[j] > v) { v = cv[j]; col = col0 + tx*8 + j; }
        }
        float* dst = logits + (size_t)row * N_CODE + col0 + tx*8;
        *(float4*)(dst)     = make_float4(cv[0], cv[1], cv[2], cv[3]);
        *(float4*)(dst + 4) = make_float4(cv[4], cv[5], cv[6], cv[7]);

        // reduce (v,col) across the 16 tx-lanes of this row group
        #pragma unroll
        for (int off = 8; off > 0; off >>= 1) {
            float ov = __shfl_xor(v, off);
            int   oc = __shfl_xor(col, off);
            if (ov > v || (ov == v && oc < col)) { v = ov; col = oc; }
        }
        if (tx == 0) {
            unsigned int u = __float_as_uint(v);
            unsigned int s = (u & 0x80000000u) ? ~u : (u | 0x80000000u);
            unsigned long long key = ((unsigned long long)s << 14) |
                                     (unsigned long long)(16383 - col);
            atomicMax(keys + row, key);
        }
    }
}

// ---- K3: per-token gather + cos-sim losses, one block per token ----
__global__ __launch_bounds__(256) void k_epilogue(
    const float* __restrict__ X,
    const float* __restrict__ SEM,
    const float* __restrict__ LRN,
    const float* __restrict__ invnx,
    const float* __restrict__ invnb,
    const unsigned long long* __restrict__ keys,
    float* __restrict__ o_idx,
    float* __restrict__ o_zq,
    float* __restrict__ o_zst,
    float* __restrict__ accum)
{
    const int tok = blockIdx.x;
    const int t = threadIdx.x;
    const int col = 16383 - (int)(keys[tok] & 16383ULL);
    const float ix = invnx[tok];
    const float ib = invnb[col];
    const float* crow = (col < N_SEM) ? (SEM + (size_t)col * DIM)
                                      : (LRN + (size_t)(col - N_SEM) * DIM);

    float4 xr = ((const float4*)(X + (size_t)tok * DIM))[t];
    float4 cr = ((const float4*)crow)[t];
    float4 xv; xv.x = xr.x*ix; xv.y = xr.y*ix; xv.z = xr.z*ix; xv.w = xr.w*ix;
    float4 zv; zv.x = cr.x*ib; zv.y = cr.y*ib; zv.z = cr.z*ib; zv.w = cr.w*ib;

    float d  = xv.x*zv.x + xv.y*zv.y + xv.z*zv.z + xv.w*zv.w;
    float nx = xv.x*xv.x + xv.y*xv.y + xv.z*xv.z + xv.w*xv.w;
    float nz = zv.x*zv.x + zv.y*zv.y + zv.z*zv.z + zv.w*zv.w;
    #pragma unroll
    for (int off = 32; off > 0; off >>= 1) {
        d  += __shfl_xor(d, off);
        nx += __shfl_xor(nx, off);
        nz += __shfl_xor(nz, off);
    }
    __shared__ float rd[4], rx[4], rz[4];
    if ((t & 63) == 0) { rd[t>>6] = d; rx[t>>6] = nx; rz[t>>6] = nz; }
    __syncthreads();

    float4 zs;
    zs.x = xv.x + (zv.x - xv.x);
    zs.y = xv.y + (zv.y - xv.y);
    zs.z = xv.z + (zv.z - xv.z);
    zs.w = xv.w + (zv.w - xv.w);
    ((float4*)o_zq)[(size_t)tok * 256 + t] = zv;
    ((float4*)o_zst)[(size_t)tok * 256 + t] = zs;

    if (t == 0) {
        float D  = rd[0]+rd[1]+rd[2]+rd[3];
        float NX = rx[0]+rx[1]+rx[2]+rx[3];
        float NZ = rz[0]+rz[1]+rz[2]+rz[3];
        float cs = D / (fmaxf(sqrtf(NX), 1e-8f) * fmaxf(sqrtf(NZ), 1e-8f));
        float per = 1.f - cs;
        o_idx[tok] = (float)col;
        atomicAdd(accum + 0, per);                 // commitment sum
        if (col >= N_SEM) {
            atomicAdd(accum + 1, per);             // vq sum
            atomicAdd(accum + 2, 1.f);             // learnable count
        }
    }
}

// ---- K4: finalize scalars ----
__global__ void k_final(const float* __restrict__ accum,
                        float* __restrict__ o_scal) {
    float commit = accum[0] / (float)N_TOK;
    float vq     = accum[1] / (accum[2] + 1e-6f);
    o_scal[0] = vq;
    o_scal[1] = commit;
    o_scal[2] = vq + 0.25f * commit;
}

extern "C" void kernel_launch(void* const* d_in, const int* in_sizes, int n_in,
                              void* d_out, int out_size, void* d_ws, size_t ws_size,
                              hipStream_t stream) {
    const float* x   = (const float*)d_in[0];   // [8192,1024] fp32
    const float* sem = (const float*)d_in[1];   // [8192,1024] fp32
    const float* lrn = (const float*)d_in[2];   // [128,1024]  fp32

    // tiny workspace: invnx[8192] f32, invnb[8320] f32, keys[8192] u64, accum[4]
    float* invnx = (float*)d_ws;
    float* invnb = invnx + N_TOK;
    unsigned long long* keys =
        (unsigned long long*)(invnb + N_CODE + 2 /* pad to 8B align */);
    float* accum = (float*)(keys + N_TOK);

    float* out      = (float*)d_out;
    float* o_logits = out;                                  // 68,157,440
    float* o_idx    = o_logits + (size_t)N_TOK * N_CODE;    // 8,192
    float* o_zq     = o_idx + N_TOK;                        // 8,388,608
    float* o_zst    = o_zq + (size_t)N_TOK * DIM;           // 8,388,608
    float* o_scal   = o_zst + (size_t)N_TOK * DIM;          // 3

    k_init<<<(N_TOK + 255) / 256, 256, 0, stream>>>(keys, accum);
    k_norms<<<N_TOK, 256, 0, stream>>>(x, invnx);
    k_norms<<<N_SEM, 256, 0, stream>>>(sem, invnb);
    k_norms<<<N_LEARN, 256, 0, stream>>>(lrn, invnb + N_SEM);

    dim3 g2(N_TOK / TM, N_CODE / TN);   // 64 x 65
    k_gemm_argmax<<<g2, 256, 0, stream>>>(x, sem, lrn, invnx, invnb,
                                          o_logits, keys);

    k_epilogue<<<N_TOK, 256, 0, stream>>>(x, sem, lrn, invnx, invnb, keys,
                                          o_idx, o_zq, o_zst, accum);
    k_final<<<1, 1, 0, stream>>>(accum, o_scal);
}